// Round 16
// baseline (428.369 us; speedup 1.0000x reference)
//
#include <hip/hip_runtime.h>
#include <stdint.h>

// Problem: N=8, d=o=16, F=512, NUM_LAYERS=3.  ALL fp32 (per reference).
// out[n,o,g] = LN_o( 0.5*(c1 + c2) )  where
//   c0 = einsum(x, W, A0); h1 = LN_o(c0)
//   c1 = einsum(x, W, A1); c2 = einsum(h1, W, A0)
// einsum(h,W,a)[n,o,g] = sum_{d,f} h[n,d,f] * W[d,f,g,o] * a[f,g]
//
// R0-R15: ~150us per 256MB W pass, invariant to bytes/requests/width/
// addressing/occupancy/prefetch/barriers/VGPR-vs-LDS path/cache-install/
// source tier (L3-resident pass B = HBM-fed pass A speed). Copy kernel on
// the same buffer: 2.55 TB/s read. Per-wave arithmetic: 11K cyc per f-iter
// vs ~500 cyc of issued work -> consistent ONLY with the 16 W loads paying
// latency sequentially (issue serialization). R2/R11 prefetch probes were
// confounded (register-copy idiom + bundled changes).
// R16 = R13 (session best, 409.5us) + #pragma unroll 4 on the f-loop:
// 64 independent loads in one scheduling region, no other change. Last
// single-variable experiment; if null, R13 structure is final.

#define FC   32    // f's per chunk
#define NCH  16    // 512 / FC

// KA (SECOND=false): in = x (8,16,512); writes c0 partials (A0) + c1 (A1).
// KB (SECOND=true):  in = c0 partials; prologue reduces+LNs into the 32 h1
//                    rows this block needs; writes c2 partials (A0).
// grid = (16 f-chunks, 32 col-tiles), 256 threads, 1 col/thread.
// Partial layout: [chunk][col][n], col = g*16+o.
template <bool SECOND>
__global__ __launch_bounds__(256)
void k_contract(const float* __restrict__ W, const float* __restrict__ A,
                const float* __restrict__ in,
                float* __restrict__ p0, float* __restrict__ p1) {
    __shared__ float sx[FC][16][8];   // 16 KB: h slices [f_local][d][n]
    __shared__ float sA0[FC][16];     //  2 KB: A0 [f_local][g_local]
    __shared__ float sA1[FC][16];     //  2 KB: A1 (pass A only)

    const int t  = threadIdx.x;       // 0..255
    const int fc = blockIdx.x;        // 0..15
    const int ct = blockIdx.y;        // 0..31
    const int f0 = fc * FC;

    if constexpr (!SECOND) {
        // transpose x slice into LDS (4096 vals, 16/thr); x 256KB, L2/L3-hot
#pragma unroll
        for (int k = 0; k < 16; ++k) {
            int idx = k * 256 + t;
            int fl = idx >> 7, d = (idx >> 3) & 15, n = idx & 7;
            sx[fl][d][n] = in[n * 8192 + d * 512 + f0 + fl];
        }
    } else {
        // reduce c0 partials over 16 chunks (4096 vals, 16/thr; 4MB, L2/L3)
#pragma unroll
        for (int k = 0; k < 16; ++k) {
            int idx = k * 256 + t;
            int fl = idx >> 7, o = (idx >> 3) & 15, n = idx & 7;
            float s = 0.f;
#pragma unroll
            for (int ch = 0; ch < NCH; ++ch)
                s += in[(((size_t)ch * 512 + f0 + fl) * 16 + o) * 8 + n];
            sx[fl][o][n] = s;
        }
        __syncthreads();
        // LayerNorm over o in place; thread (fl,n) owns column sx[fl][*][n]
        {
            int fl = t >> 3, n = t & 7;   // 32*8 = 256 = blockDim
            float m = 0.f, v = 0.f;
#pragma unroll
            for (int oo = 0; oo < 16; ++oo) { float y = sx[fl][oo][n]; m += y; v += y * y; }
            m *= (1.f / 16.f);
            v = v * (1.f / 16.f) - m * m;
            float r = rsqrtf(v + 1e-5f);
#pragma unroll
            for (int oo = 0; oo < 16; ++oo) sx[fl][oo][n] = (sx[fl][oo][n] - m) * r;
        }
    }
    // stage A slices: 512 vals per mat, 2/thr
#pragma unroll
    for (int k = 0; k < 2; ++k) {
        int idx = k * 256 + t;
        int fl = idx >> 4, gl = idx & 15;
        sA0[fl][gl] = A[(size_t)(f0 + fl) * 512 + ct * 16 + gl];
        if constexpr (!SECOND)
            sA1[fl][gl] = A[262144 + (size_t)(f0 + fl) * 512 + ct * 16 + gl];
    }
    __syncthreads();

    const int gl  = t >> 4;            // g_local 0..15
    const int col = ct * 256 + t;      // global column (g*16+o)
    const float* Wc = W + col;         // + d*4194304 + f*8192

    float c0[8], c1[8];
#pragma unroll
    for (int n = 0; n < 8; ++n) { c0[n] = 0.f; c1[n] = 0.f; }

    // unroll 4: expose 64 independent W loads per scheduling region so the
    // compiler batches issue across iterations (the single-variable probe
    // of the issue-serialization theory; no register-copy prefetch idiom).
#pragma unroll 4
    for (int s = 0; s < FC; ++s) {
        const int fl = SECOND ? (FC - 1 - s) : s;   // serpentine in pass B
        const int f  = f0 + fl;

        float w[16];
#pragma unroll
        for (int d = 0; d < 16; ++d)
            w[d] = __builtin_nontemporal_load(Wc + (size_t)d * 4194304 + (size_t)f * 8192);

        float p[8];
#pragma unroll
        for (int n = 0; n < 8; ++n) p[n] = 0.f;
#pragma unroll
        for (int d = 0; d < 16; ++d) {
            float4 xa = *reinterpret_cast<const float4*>(&sx[fl][d][0]);
            float4 xb = *reinterpret_cast<const float4*>(&sx[fl][d][4]);
            p[0] = fmaf(xa.x, w[d], p[0]);
            p[1] = fmaf(xa.y, w[d], p[1]);
            p[2] = fmaf(xa.z, w[d], p[2]);
            p[3] = fmaf(xa.w, w[d], p[3]);
            p[4] = fmaf(xb.x, w[d], p[4]);
            p[5] = fmaf(xb.y, w[d], p[5]);
            p[6] = fmaf(xb.z, w[d], p[6]);
            p[7] = fmaf(xb.w, w[d], p[7]);
        }

        const float a0 = sA0[fl][gl];
#pragma unroll
        for (int n = 0; n < 8; ++n) c0[n] = fmaf(a0, p[n], c0[n]);
        if constexpr (!SECOND) {
            const float a1 = sA1[fl][gl];
#pragma unroll
            for (int n = 0; n < 8; ++n) c1[n] = fmaf(a1, p[n], c1[n]);
        }
    }

    // partials [chunk][col][n]: thread's 8 floats contiguous, coalesced.
    size_t base = ((size_t)fc * 8192 + col) * 8;
    float4* dst0 = reinterpret_cast<float4*>(p0 + base);
    dst0[0] = make_float4(c0[0], c0[1], c0[2], c0[3]);
    dst0[1] = make_float4(c0[4], c0[5], c0[6], c0[7]);
    if constexpr (!SECOND) {
        float4* dst1 = reinterpret_cast<float4*>(p1 + base);
        dst1[0] = make_float4(c1[0], c1[1], c1[2], c1[3]);
        dst1[1] = make_float4(c1[4], c1[5], c1[6], c1[7]);
    }
}

// KF: y = 0.5*(c1+c2) reduced over 16 chunks, LayerNorm over o, out [n][o][g]
__global__ __launch_bounds__(128)
void k_final(const float* __restrict__ p1, const float* __restrict__ p2,
             float* __restrict__ out) {
    __shared__ float sh[16][8];
    int g = blockIdx.x;                 // 0..511
    int t = threadIdx.x;                // 0..127
    int o = t >> 3, n = t & 7;
    float s0 = 0.f, s1 = 0.f;
#pragma unroll
    for (int ch = 0; ch < NCH; ++ch) {
        size_t idx = (((size_t)ch * 512 + g) * 16 + o) * 8 + n;
        s0 += p1[idx];
        s1 += p2[idx];
    }
    float s = 0.5f * (s0 + s1);
    sh[o][n] = s;
    __syncthreads();
    float m = 0.f, v = 0.f;
#pragma unroll
    for (int oo = 0; oo < 16; ++oo) { float y = sh[oo][n]; m += y; v += y * y; }
    m *= (1.f / 16.f);
    v = v * (1.f / 16.f) - m * m;
    float r = rsqrtf(v + 1e-5f);
    out[n * 8192 + o * 512 + g] = (s - m) * r;
}

extern "C" void kernel_launch(void* const* d_in, const int* in_sizes, int n_in,
                              void* d_out, int out_size, void* d_ws, size_t ws_size,
                              hipStream_t stream) {
    const float* x = (const float*)d_in[0];   // (8,16,512)      fp32
    const float* W = (const float*)d_in[1];   // (16,512,512,16) fp32
    const float* A = (const float*)d_in[2];   // (2,512,512)     fp32
    float* out = (float*)d_out;               // (8,16,512)      fp32

    float* ws  = (float*)d_ws;
    float* c0p = ws;                    // 1048576 floats: c0 partials [16][8192][8]
    float* c1p = c0p + 1048576;         // 1048576 floats: c1 partials
    float* c2p = c1p + 1048576;         // 1048576 floats: c2 partials
    // total ws use: 12 MB

    k_contract<false><<<dim3(NCH, 32), 256, 0, stream>>>(W, A, x,   c0p, c1p);
    k_contract<true ><<<dim3(NCH, 32), 256, 0, stream>>>(W, A, c0p, c2p, nullptr);
    k_final<<<512, 128, 0, stream>>>(c1p, c2p, out);
}

// Round 17
// 411.928 us; speedup vs baseline: 1.0399x; 1.0399x over previous
//
#include <hip/hip_runtime.h>
#include <stdint.h>

// Problem: N=8, d=o=16, F=512, NUM_LAYERS=3.  ALL fp32 (per reference).
// out[n,o,g] = LN_o( 0.5*(c1 + c2) )  where
//   c0 = einsum(x, W, A0); h1 = LN_o(c0)
//   c1 = einsum(x, W, A1); c2 = einsum(h1, W, A0)
// einsum(h,W,a)[n,o,g] = sum_{d,f} h[n,d,f] * W[d,f,g,o] * a[f,g]
//
// FINAL (R17 = R13 revert, session best 409.5us). 16 rounds of single-
// variable falsification: per-pass consume-attached W stream rate on this
// box is ~1.7 TB/s, invariant to bytes (fp16 R9), requests/width (R5/R7),
// addressing (R7), occupancy 8->32 w/CU (R15), prefetch (R11/R16),
// barriers (R4), VGPR-vs-LDS-DMA return (R12), cache-install nt (R13),
// source tier (R10: L3-resident = HBM speed), buffer identity (R14: ws
// copy = input; same-box copy kernel 2.55 TB/s read-side). R10 counters:
// HBM 8%, VALU 6%, occ 24% -> no busy pipe; residual 1.5x gap to copy-rate
// has no counter signature. Structural floor: 2 W passes (h1 = LN(sum c0)
// forces the dependency) + ~16us small kernels + ~95us harness-fixed
// inter-dispatch overhead = ~409us.

#define FC   32    // f's per chunk
#define NCH  16    // 512 / FC

// KA (SECOND=false): in = x (8,16,512); writes c0 partials (A0) + c1 (A1).
// KB (SECOND=true):  in = c0 partials; prologue reduces+LNs into the 32 h1
//                    rows this block needs; writes c2 partials (A0).
// grid = (16 f-chunks, 32 col-tiles), 256 threads, 1 col/thread.
// Partial layout: [chunk][col][n], col = g*16+o.
template <bool SECOND>
__global__ __launch_bounds__(256)
void k_contract(const float* __restrict__ W, const float* __restrict__ A,
                const float* __restrict__ in,
                float* __restrict__ p0, float* __restrict__ p1) {
    __shared__ float sx[FC][16][8];   // 16 KB: h slices [f_local][d][n]
    __shared__ float sA0[FC][16];     //  2 KB: A0 [f_local][g_local]
    __shared__ float sA1[FC][16];     //  2 KB: A1 (pass A only)

    const int t  = threadIdx.x;       // 0..255
    const int fc = blockIdx.x;        // 0..15
    const int ct = blockIdx.y;        // 0..31
    const int f0 = fc * FC;

    if constexpr (!SECOND) {
        // transpose x slice into LDS (4096 vals, 16/thr); x 256KB, L2/L3-hot
#pragma unroll
        for (int k = 0; k < 16; ++k) {
            int idx = k * 256 + t;
            int fl = idx >> 7, d = (idx >> 3) & 15, n = idx & 7;
            sx[fl][d][n] = in[n * 8192 + d * 512 + f0 + fl];
        }
    } else {
        // reduce c0 partials over 16 chunks (4096 vals, 16/thr; 4MB, L2/L3)
#pragma unroll
        for (int k = 0; k < 16; ++k) {
            int idx = k * 256 + t;
            int fl = idx >> 7, o = (idx >> 3) & 15, n = idx & 7;
            float s = 0.f;
#pragma unroll
            for (int ch = 0; ch < NCH; ++ch)
                s += in[(((size_t)ch * 512 + f0 + fl) * 16 + o) * 8 + n];
            sx[fl][o][n] = s;
        }
        __syncthreads();
        // LayerNorm over o in place; thread (fl,n) owns column sx[fl][*][n]
        {
            int fl = t >> 3, n = t & 7;   // 32*8 = 256 = blockDim
            float m = 0.f, v = 0.f;
#pragma unroll
            for (int oo = 0; oo < 16; ++oo) { float y = sx[fl][oo][n]; m += y; v += y * y; }
            m *= (1.f / 16.f);
            v = v * (1.f / 16.f) - m * m;
            float r = rsqrtf(v + 1e-5f);
#pragma unroll
            for (int oo = 0; oo < 16; ++oo) sx[fl][oo][n] = (sx[fl][oo][n] - m) * r;
        }
    }
    // stage A slices: 512 vals per mat, 2/thr
#pragma unroll
    for (int k = 0; k < 2; ++k) {
        int idx = k * 256 + t;
        int fl = idx >> 4, gl = idx & 15;
        sA0[fl][gl] = A[(size_t)(f0 + fl) * 512 + ct * 16 + gl];
        if constexpr (!SECOND)
            sA1[fl][gl] = A[262144 + (size_t)(f0 + fl) * 512 + ct * 16 + gl];
    }
    __syncthreads();

    const int gl  = t >> 4;            // g_local 0..15
    const int col = ct * 256 + t;      // global column (g*16+o)
    const float* Wc = W + col;         // + d*4194304 + f*8192

    float c0[8], c1[8];
#pragma unroll
    for (int n = 0; n < 8; ++n) { c0[n] = 0.f; c1[n] = 0.f; }

    for (int s = 0; s < FC; ++s) {
        const int fl = SECOND ? (FC - 1 - s) : s;   // serpentine in pass B
        const int f  = f0 + fl;

        // NONTEMPORAL W loads: stream-once data, skip cache install.
        float w[16];
#pragma unroll
        for (int d = 0; d < 16; ++d)
            w[d] = __builtin_nontemporal_load(Wc + (size_t)d * 4194304 + (size_t)f * 8192);

        float p[8];
#pragma unroll
        for (int n = 0; n < 8; ++n) p[n] = 0.f;
#pragma unroll
        for (int d = 0; d < 16; ++d) {
            float4 xa = *reinterpret_cast<const float4*>(&sx[fl][d][0]);
            float4 xb = *reinterpret_cast<const float4*>(&sx[fl][d][4]);
            p[0] = fmaf(xa.x, w[d], p[0]);
            p[1] = fmaf(xa.y, w[d], p[1]);
            p[2] = fmaf(xa.z, w[d], p[2]);
            p[3] = fmaf(xa.w, w[d], p[3]);
            p[4] = fmaf(xb.x, w[d], p[4]);
            p[5] = fmaf(xb.y, w[d], p[5]);
            p[6] = fmaf(xb.z, w[d], p[6]);
            p[7] = fmaf(xb.w, w[d], p[7]);
        }

        const float a0 = sA0[fl][gl];
#pragma unroll
        for (int n = 0; n < 8; ++n) c0[n] = fmaf(a0, p[n], c0[n]);
        if constexpr (!SECOND) {
            const float a1 = sA1[fl][gl];
#pragma unroll
            for (int n = 0; n < 8; ++n) c1[n] = fmaf(a1, p[n], c1[n]);
        }
    }

    // partials [chunk][col][n]: thread's 8 floats contiguous, coalesced.
    size_t base = ((size_t)fc * 8192 + col) * 8;
    float4* dst0 = reinterpret_cast<float4*>(p0 + base);
    dst0[0] = make_float4(c0[0], c0[1], c0[2], c0[3]);
    dst0[1] = make_float4(c0[4], c0[5], c0[6], c0[7]);
    if constexpr (!SECOND) {
        float4* dst1 = reinterpret_cast<float4*>(p1 + base);
        dst1[0] = make_float4(c1[0], c1[1], c1[2], c1[3]);
        dst1[1] = make_float4(c1[4], c1[5], c1[6], c1[7]);
    }
}

// KF: y = 0.5*(c1+c2) reduced over 16 chunks, LayerNorm over o, out [n][o][g]
__global__ __launch_bounds__(128)
void k_final(const float* __restrict__ p1, const float* __restrict__ p2,
             float* __restrict__ out) {
    __shared__ float sh[16][8];
    int g = blockIdx.x;                 // 0..511
    int t = threadIdx.x;                // 0..127
    int o = t >> 3, n = t & 7;
    float s0 = 0.f, s1 = 0.f;
#pragma unroll
    for (int ch = 0; ch < NCH; ++ch) {
        size_t idx = (((size_t)ch * 512 + g) * 16 + o) * 8 + n;
        s0 += p1[idx];
        s1 += p2[idx];
    }
    float s = 0.5f * (s0 + s1);
    sh[o][n] = s;
    __syncthreads();
    float m = 0.f, v = 0.f;
#pragma unroll
    for (int oo = 0; oo < 16; ++oo) { float y = sh[oo][n]; m += y; v += y * y; }
    m *= (1.f / 16.f);
    v = v * (1.f / 16.f) - m * m;
    float r = rsqrtf(v + 1e-5f);
    out[n * 8192 + o * 512 + g] = (s - m) * r;
}

extern "C" void kernel_launch(void* const* d_in, const int* in_sizes, int n_in,
                              void* d_out, int out_size, void* d_ws, size_t ws_size,
                              hipStream_t stream) {
    const float* x = (const float*)d_in[0];   // (8,16,512)      fp32
    const float* W = (const float*)d_in[1];   // (16,512,512,16) fp32
    const float* A = (const float*)d_in[2];   // (2,512,512)     fp32
    float* out = (float*)d_out;               // (8,16,512)      fp32

    float* ws  = (float*)d_ws;
    float* c0p = ws;                    // 1048576 floats: c0 partials [16][8192][8]
    float* c1p = c0p + 1048576;         // 1048576 floats: c1 partials
    float* c2p = c1p + 1048576;         // 1048576 floats: c2 partials
    // total ws use: 12 MB

    k_contract<false><<<dim3(NCH, 32), 256, 0, stream>>>(W, A, x,   c0p, c1p);
    k_contract<true ><<<dim3(NCH, 32), 256, 0, stream>>>(W, A, c0p, c2p, nullptr);
    k_final<<<512, 128, 0, stream>>>(c1p, c2p, out);
}